// Round 1
// baseline (162.772 us; speedup 1.0000x reference)
//
#include <hip/hip_runtime.h>

// RSNN: B=32, T=500, N_IN=512, N_HID=2048.
// Key mathematical fact: reset = (mem > -55). Once ALL neurons of a batch have
// mem > -55 at the top of a step, mem becomes exactly 0 for all of them
// (mem = base*(1-reset)), and mem==0 > -55 is absorbing: the input/recurrent
// matmuls are multiplied by exactly 0.0 forever after. From that step on the
// output is a closed-form refractory state machine (period-5 spiking).
//
// Kernel 1 (scan): faithful general recurrence with a per-step block vote;
//   exits to "fast mode" permanently when the vote proves absorption.
// Kernel 2 (expand): writes the closed-form spike pattern for t >= t_entry[b].
// For the benchmark data the vote fails at t=0, so kernel 2 (pure 131 MB
// write) dominates: HBM-write-bound.

#define T_STEPS   500
#define BATCH     32
#define N_INP     512
#define N_HID     2048
#define THRESH    (-55.0f)
#define BETA_V    0.95f
#define REST      70.0f
#define REFRAC_P  5

__global__ __launch_bounds__(1024) void rsnn_scan(
    const float* __restrict__ x,       // [B, T, N_INP]
    const float* __restrict__ mem0,    // [B, N_HID]
    const float* __restrict__ W_in,    // [N_HID, N_INP]
    const float* __restrict__ b_in,    // [N_HID]
    const float* __restrict__ W_rec,   // [N_HID, N_HID]
    const float* __restrict__ b_rec,   // [N_HID]
    float* __restrict__ out,           // [T, B, N_HID]
    int* __restrict__ tEntry,          // [B]
    unsigned char* __restrict__ refracOut) // [B, N_HID]
{
    const int b   = blockIdx.x;
    const int tid = threadIdx.x;
    const int hh[2] = { tid, tid + 1024 };

    __shared__ float spkLDS[N_HID];
    __shared__ int   flag;

    float mem[2];
    int   rr[2] = { 0, 0 };
    float spk[2] = { 0.f, 0.f };

#pragma unroll
    for (int j = 0; j < 2; ++j) mem[j] = mem0[b * N_HID + hh[j]];
#pragma unroll
    for (int j = 0; j < 2; ++j) spkLDS[hh[j]] = 0.f;

    int te = T_STEPS;

    for (int t = 0; t < T_STEPS; ++t) {
        if (tid == 0) flag = 0;
        __syncthreads();
        if (!(mem[0] > THRESH) || !(mem[1] > THRESH)) flag = 1;
        __syncthreads();
        if (flag == 0) { te = t; break; }  // block-uniform: absorbing fast mode

        // ---- general (slow) step — never executed on benchmark data ----
#pragma unroll
        for (int j = 0; j < 2; ++j) {
            const int h = hh[j];
            rr[j] = max(rr[j] - 1, 0);
            const bool reset = (mem[j] > THRESH);
            float m;
            if (!reset) {
                float rec = 0.f;
                const float* wr = W_rec + (size_t)h * N_HID;
                for (int k = 0; k < N_HID; ++k) rec += spkLDS[k] * wr[k];
                float cur = b_in[h];
                const float* xi = x + ((size_t)b * T_STEPS + t) * N_INP;
                const float* wi = W_in + (size_t)h * N_INP;
                for (int k = 0; k < N_INP; ++k) cur += xi[k] * wi[k];
                m = BETA_V * (mem[j] + REST) + cur + rec + b_rec[h] - REST;
            } else {
                m = 0.f;
            }
            mem[j] = m;
            spk[j] = ((mem[j] > THRESH) && (rr[j] == 0)) ? 1.f : 0.f;
            if (spk[j] > 0.f) rr[j] = REFRAC_P;
            out[(size_t)t * (BATCH * N_HID) + (size_t)b * N_HID + h] = spk[j];
        }
        __syncthreads();  // finish spkLDS reads before overwrite
#pragma unroll
        for (int j = 0; j < 2; ++j) spkLDS[hh[j]] = spk[j];
        // next iteration's vote barrier orders these writes before reads
    }

#pragma unroll
    for (int j = 0; j < 2; ++j)
        refracOut[b * N_HID + hh[j]] = (unsigned char)rr[j];
    if (tid == 0) tEntry[b] = te;
}

// One thread per 4 consecutive output elements (same t, same b).
__global__ __launch_bounds__(256) void rsnn_expand(
    float* __restrict__ out,
    const int* __restrict__ tEntry,
    const unsigned char* __restrict__ refrac)
{
    const unsigned idx4 = (blockIdx.x * 256u + threadIdx.x) * 4u; // elem index
    const int t   = (int)(idx4 >> 16);        // B*N_HID = 65536 = 2^16
    const int rem = (int)(idx4 & 65535u);
    const int b   = rem >> 11;                // N_HID = 2048 = 2^11
    const int h   = rem & 2047;

    const int te = tEntry[b];
    if (t < te) return;                       // slow region already written by scan

    const int s  = t - te;
    const int sm = s % 5;

    uchar4 R = *(const uchar4*)(refrac + b * N_HID + h);
    float4 o;
    {
        int s0 = R.x ? (int)R.x - 1 : 0;
        o.x = (s >= s0 && sm == s0) ? 1.f : 0.f;
    }
    {
        int s0 = R.y ? (int)R.y - 1 : 0;
        o.y = (s >= s0 && sm == s0) ? 1.f : 0.f;
    }
    {
        int s0 = R.z ? (int)R.z - 1 : 0;
        o.z = (s >= s0 && sm == s0) ? 1.f : 0.f;
    }
    {
        int s0 = R.w ? (int)R.w - 1 : 0;
        o.w = (s >= s0 && sm == s0) ? 1.f : 0.f;
    }
    *(float4*)(out + idx4) = o;
}

extern "C" void kernel_launch(void* const* d_in, const int* in_sizes, int n_in,
                              void* d_out, int out_size, void* d_ws, size_t ws_size,
                              hipStream_t stream) {
    const float* x     = (const float*)d_in[0];
    const float* mem0  = (const float*)d_in[1];
    const float* W_in  = (const float*)d_in[2];
    const float* b_in  = (const float*)d_in[3];
    const float* W_rec = (const float*)d_in[4];
    const float* b_rec = (const float*)d_in[5];
    float* out = (float*)d_out;

    int* tEntry = (int*)d_ws;                                   // 32 ints
    unsigned char* refrac = (unsigned char*)d_ws + 128;         // B*N_HID bytes

    rsnn_scan<<<BATCH, 1024, 0, stream>>>(x, mem0, W_in, b_in, W_rec, b_rec,
                                          out, tEntry, refrac);

    const unsigned total = (unsigned)T_STEPS * BATCH * N_HID;   // 32,768,000
    const unsigned blocks = total / (256u * 4u);                // 32,000
    rsnn_expand<<<blocks, 256, 0, stream>>>(out, tEntry, refrac);
}